// Round 13
// baseline (161.548 us; speedup 1.0000x reference)
//
#include <hip/hip_runtime.h>
#include <hip/hip_cooperative_groups.h>
#include <math.h>

namespace cg = cooperative_groups;

#define HH 352
#define WW 352
#define WPR 11                      // words per row = 352/32
#define NWORDS (HH * WPR)           // words per image = 3872
#define INF_I (1 << 30)

// ---------------------------------------------------------------------------
// Single cooperative kernel, 484 blocks x 256 threads (1936 waves, fully
// co-resident: 8 blocks/CU possible, we need ~1.9).
// Phase A: pack target!=0 into a row-major bitmask (1 word / thread, first
//          15488 threads; 8 float4 loads each) + pad word.  grid.sync()
// Phase B: 4 px/thread: d2 = min (di^2+dj^2) over opposite pixels == |sdt|^2
//          (one of dist_fg/dist_bg is 0 everywhere). 5x5 window via one 8-bit
//          row-extract shared by the 4 px; exact when it hits (<=8 < 9 <=
//          anything outside); boundary bits masked AFTER the opposite-XOR.
//          Rare exact expanding-ring fallback on raw target (P~2^-24/px).
//          w = exp(-sqrt(d2)/5) (no-opposite => 0, matches reference
//          underflow); bce; block reduce -> 4 plain floats/block. grid.sync()
// Phase C: block 0: per-sample reduce of 121 entries; loss separability
//          sum bce*(1+0.5*wn) = S1 + 0.5*(SW - wmin*S1)/den; f64; mean->out.
// ---------------------------------------------------------------------------
__global__ __launch_bounds__(256) void mono_kernel(const float* __restrict__ pred,
                                                   const float* __restrict__ target,
                                                   unsigned int* __restrict__ mask,
                                                   float* __restrict__ bmin,
                                                   float* __restrict__ bmax,
                                                   float* __restrict__ bs1,
                                                   float* __restrict__ bsw,
                                                   float* __restrict__ out,
                                                   int Bc, int nPB, double invN)
{
    cg::grid_group grid = cg::this_grid();
    const int HW = HH * WW;
    const int nWordsAll = (HW / 32) * Bc;           // 15488
    int g = blockIdx.x * 256 + threadIdx.x;         // 0..123903

    // hoist pred: issue before pack so HBM latency hides under phase A+sync
    float4 p4 = *(const float4*)(pred + (g << 2));

    // ---- Phase A: pack ----
    if (g < nWordsAll) {
        const float4* t4 = (const float4*)(target + (g << 5));
        unsigned int word = 0u;
        #pragma unroll
        for (int k = 0; k < 8; ++k) {
            float4 v = t4[k];
            unsigned int nib = (v.x != 0.f ? 1u : 0u) | (v.y != 0.f ? 2u : 0u) |
                               (v.z != 0.f ? 4u : 0u) | (v.w != 0.f ? 8u : 0u);
            word |= nib << (4 * k);
        }
        mask[g] = word;
        if (g == 0) mask[nWordsAll] = 0u;           // pad word
    }
    grid.sync();

    // ---- Phase B: windowed min-d2 + bce + block reduce ----
    int px = g << 2;
    int b = px / HW;
    int r0 = px - b * HW;
    int i = r0 / WW;
    int j0 = r0 - i * WW;                           // multiple of 4
    const unsigned int* mimg = mask + b * NWORDS;

    int s = j0 - 2;
    unsigned int w8[5];
    #pragma unroll
    for (int dy = -2; dy <= 2; ++dy) {
        int iy = i + dy;
        bool rowok = (iy >= 0) && (iy < HH);
        int iyc = rowok ? iy : 0;
        const unsigned int* mrow = mimg + iyc * WPR;
        unsigned int v;
        if (j0 == 0) {
            v = (mrow[0] << 2) & 0xFCu;             // cols 0..5 at bits 2..7
        } else {
            int u2 = s >> 5, sh = s & 31;
            unsigned long long M = (unsigned long long)mrow[u2] |
                                   ((unsigned long long)mrow[u2 + 1] << 32);
            v = (unsigned int)(M >> sh) & 0xFFu;
        }
        w8[dy + 2] = rowok ? v : 0x100u;            // 0x100 = invalid-row sentinel
    }
    unsigned int c8 = w8[2];

    int best[4];
    bool fgq[4];
    #pragma unroll
    for (int q = 0; q < 4; ++q) {
        int j = j0 + q;
        bool fg = (c8 >> (q + 2)) & 1u;
        fgq[q] = fg;
        unsigned int valid = 31u;
        if (j < 2)      valid &= (31u << (2 - j)) & 31u;
        if (j > WW - 3) valid &= 31u >> (j - (WW - 3));
        int bq = INF_I;
        #pragma unroll
        for (int dy = -2; dy <= 2; ++dy) {
            unsigned int rw = w8[dy + 2];
            const int dy2 = dy * dy;
            unsigned int w5 = (rw >> q) & 31u;
            unsigned int opp = (fg ? ~w5 : w5) & valid;
            if (rw & 0x100u) opp = 0u;
            int rowd2 = (opp & 4u)  ? dy2 :
                        (opp & 10u) ? dy2 + 1 :
                        (opp & 17u) ? dy2 + 4 : INF_I;
            bq = rowd2 < bq ? rowd2 : bq;
        }
        best[q] = bq;
    }

    #pragma unroll
    for (int q = 0; q < 4; ++q) {
        if (best[q] == INF_I) {                     // rare exact fallback
            const float* timg = target + b * HW;
            int j = j0 + q;
            bool fg = fgq[q];
            int bq = best[q];
            for (int rad = 3; rad <= 351; ++rad) {
                if (rad * rad >= bq) break;
                int y0 = i - rad, y1 = i + rad, x0 = j - rad, x1 = j + rad;
                int xa = x0 < 0 ? 0 : x0, xb = x1 >= WW ? WW - 1 : x1;
                for (int pass = 0; pass < 2; ++pass) {
                    int iy = pass ? y1 : y0;
                    if (iy < 0 || iy >= HH) continue;
                    int dy2 = (iy - i) * (iy - i);
                    for (int jx = xa; jx <= xb; ++jx)
                        if ((timg[iy * WW + jx] != 0.0f) != fg) {
                            int cd = dy2 + (jx - j) * (jx - j);
                            if (cd < bq) bq = cd;
                        }
                }
                int ya = y0 + 1 < 0 ? 0 : y0 + 1, yb = y1 - 1 >= HH ? HH - 1 : y1 - 1;
                for (int pass = 0; pass < 2; ++pass) {
                    int jx = pass ? x1 : x0;
                    if (jx < 0 || jx >= WW) continue;
                    int dx2 = (jx - j) * (jx - j);
                    for (int iy = ya; iy <= yb; ++iy)
                        if ((timg[iy * WW + jx] != 0.0f) != fg) {
                            int cd = dx2 + (iy - i) * (iy - i);
                            if (cd < bq) bq = cd;
                        }
                }
            }
            best[q] = bq;
        }
    }

    float lmin = 3e38f, lmax = 0.0f, ls1 = 0.0f, lsw = 0.0f;
    float pv[4] = {p4.x, p4.y, p4.z, p4.w};
    #pragma unroll
    for (int q = 0; q < 4; ++q) {
        float w = (best[q] == INF_I) ? 0.0f
                                     : expf(-sqrtf((float)best[q]) * 0.2f); // SIGMA=5
        float p = pv[q];
        float t = fgq[q] ? 1.0f : 0.0f;
        float bce = fmaxf(p, 0.0f) - p * t + log1pf(expf(-fabsf(p)));
        lmin = fminf(lmin, w);
        lmax = fmaxf(lmax, w);
        ls1 += bce;
        lsw += bce * w;
    }

    #pragma unroll
    for (int off = 32; off > 0; off >>= 1) {
        lmin = fminf(lmin, __shfl_down(lmin, off));
        lmax = fmaxf(lmax, __shfl_down(lmax, off));
        ls1 += __shfl_down(ls1, off);
        lsw += __shfl_down(lsw, off);
    }
    __shared__ float s4[4][4];
    int wid = threadIdx.x >> 6;
    if ((threadIdx.x & 63) == 0) {
        s4[0][wid] = lmin; s4[1][wid] = lmax; s4[2][wid] = ls1; s4[3][wid] = lsw;
    }
    __syncthreads();
    if (threadIdx.x == 0) {
        float m0 = s4[0][0], m1 = s4[1][0], a = s4[2][0], c2 = s4[3][0];
        #pragma unroll
        for (int t2 = 1; t2 < 4; ++t2) {
            m0 = fminf(m0, s4[0][t2]);
            m1 = fmaxf(m1, s4[1][t2]);
            a += s4[2][t2];
            c2 += s4[3][t2];
        }
        bmin[blockIdx.x] = m0; bmax[blockIdx.x] = m1;
        bs1[blockIdx.x] = a;   bsw[blockIdx.x] = c2;
    }
    grid.sync();

    // ---- Phase C: block 0 finalize ----
    if (blockIdx.x == 0) {
        __shared__ double sl[4];
        int lane = threadIdx.x & 63;
        double mysum = 0.0;
        for (int bb = wid; bb < Bc; bb += 4) {
            float qmin = 3e38f, qmax = 0.0f;
            double ds1 = 0.0, dsw = 0.0;
            for (int t = lane; t < nPB; t += 64) {
                int o = bb * nPB + t;
                qmin = fminf(qmin, bmin[o]);
                qmax = fmaxf(qmax, bmax[o]);
                ds1 += (double)bs1[o];
                dsw += (double)bsw[o];
            }
            #pragma unroll
            for (int off = 32; off > 0; off >>= 1) {
                qmin = fminf(qmin, __shfl_down(qmin, off));
                qmax = fmaxf(qmax, __shfl_down(qmax, off));
                ds1 += __shfl_down(ds1, off);
                dsw += __shfl_down(dsw, off);
            }
            if (lane == 0) {
                double wmin = (double)qmin;
                double den  = (double)qmax - wmin + 1e-6;
                mysum += ds1 + 0.5 * (dsw - wmin * ds1) / den;
            }
        }
        if (lane == 0) sl[wid] = mysum;
        __syncthreads();
        if (threadIdx.x == 0) {
            double tot = 0.0;
            #pragma unroll
            for (int q = 0; q < 4; ++q) tot += sl[q];
            out[0] = (float)(tot * invN);
        }
    }
}

extern "C" void kernel_launch(void* const* d_in, const int* in_sizes, int n_in,
                              void* d_out, int out_size, void* d_ws, size_t ws_size,
                              hipStream_t stream)
{
    const float* pred   = (const float*)d_in[0];
    const float* target = (const float*)d_in[1];
    float* out = (float*)d_out;

    const int N = in_sizes[0];            // 495616
    int B = N / (HH * WW);                // 4
    const int nBlk = (N / 4) / 256;       // 484 blocks (exact)
    int nPB = (HH * WW) / 1024;           // 121 blocks per sample (exact)

    float* bmin = (float*)d_ws;
    float* bmax = bmin + nBlk;
    float* bs1  = bmax + nBlk;
    float* bsw  = bs1 + nBlk;
    unsigned int* mask = (unsigned int*)(bsw + nBlk);   // N/32 + 1 u32

    double invN = 1.0 / (double)N;
    void* args[] = {(void*)&pred, (void*)&target, (void*)&mask,
                    (void*)&bmin, (void*)&bmax, (void*)&bs1, (void*)&bsw,
                    (void*)&out, (void*)&B, (void*)&nPB, (void*)&invN};

    hipLaunchCooperativeKernel((void*)mono_kernel, dim3(nBlk), dim3(256),
                               args, 0, stream);
}